// Round 13
// baseline (351.219 us; speedup 1.0000x reference)
//
#include <hip/hip_runtime.h>
#include <stdint.h>
#include <stddef.h>

typedef unsigned short u16;
typedef __attribute__((ext_vector_type(8))) short  bf16x8;   // 8 bf16 = 4 VGPR (MFMA A/B frag)
typedef __attribute__((ext_vector_type(4))) unsigned short u16x4;
typedef __attribute__((ext_vector_type(4))) float  f32x4;

#define DEVI __device__ __forceinline__

DEVI float bf2f(u16 u){ union{uint32_t i; float f;} v; v.i = ((uint32_t)u)<<16; return v.f; }
DEVI u16 f2bf(float f){ union{float f; uint32_t i;} v; v.f=f; uint32_t r = v.i + 0x7fffu + ((v.i>>16)&1u); return (u16)(r>>16); }

DEVI void gload_lds16(const void* g, void* l){
  __builtin_amdgcn_global_load_lds((const __attribute__((address_space(1))) void*)g,
                                   (__attribute__((address_space(3))) void*)l, 16, 0, 0);
}

// ---------------- fused prep: x->bf16 cvt + Wqkv^T + Wproj^T (one launch) ----------------
__global__ __launch_bounds__(256) void k_prep(
    const float* __restrict__ x,     u16* __restrict__ xb,
    const float* __restrict__ Wqkv,  u16* __restrict__ WqkvT,
    const float* __restrict__ Wproj, u16* __restrict__ WprojT)
{
  __shared__ float tile[32][33];
  int bid = blockIdx.x;
  int tid = threadIdx.x;
  if (bid < 2048){                       // cvt x (8,388,608 f32)
    int i = (bid*256 + tid)*4;
    const int st = 2048*256*4;
    for (; i < 8388608; i += st){
      f32x4 v = *(const f32x4*)(x + i);
      u16x4 o;
      #pragma unroll
      for (int j=0;j<4;j++) o[j] = f2bf(v[j]);
      *(u16x4*)(xb + i) = o;
    }
    return;
  }
  const float* in; u16* out; int K, N, nb, kb;
  if (bid < 2048 + 12288){               // Wqkv [2048][6144] -> [6144][2048]
    int b2 = bid - 2048; in = Wqkv; out = WqkvT; K = 2048; N = 6144;
    nb = (b2 % 192)*32; kb = (b2 / 192)*32;
  } else {                               // Wproj [2048][2048] -> [2048][2048]
    int b3 = bid - 2048 - 12288; in = Wproj; out = WprojT; K = 2048; N = 2048;
    nb = (b3 % 64)*32; kb = (b3 / 64)*32;
  }
  int tx = tid & 31, ty = tid >> 5;
  #pragma unroll
  for (int i=0;i<32;i+=8)
    tile[ty+i][tx] = in[(size_t)(kb+ty+i)*N + nb+tx];
  __syncthreads();
  #pragma unroll
  for (int i=0;i<32;i+=8)
    out[(size_t)(nb+ty+i)*K + kb+tx] = f2bf(tile[tx][ty+i]);
}

// ================= 128x256 8-wave GEMM, 2-phase/K-tile, 3-deep slab rotation ==========
// R8-exact (proven 121 us GEMM1). XCD-local bn-chunk mapping keeps B-panels L2-resident.
#define STG_A(SLAB, GSRC) \
  gload_lds16((GSRC) + off0, (SLAB) + tid*8);
#define STG_B(SLAB, GSRC) \
  gload_lds16((GSRC) + off0, (SLAB) + tid*8); \
  gload_lds16((GSRC) + off1, (SLAB) + 4096 + tid*8);

#define RD4(SLAB, ROWBASE, DST) \
  { _Pragma("unroll") for (int f=0; f<4; f++){ \
      int row_ = (ROWBASE) + f*16 + lr; \
      int rp_ = row_>>1; \
      int slot_ = ((((row_&1)<<2) | lg) ^ (rp_&7)); \
      DST[f] = *(const bf16x8*)((const char*)(SLAB) + rp_*128 + slot_*16); } }

#define MM16(AA, BB) \
  __builtin_amdgcn_s_setprio(1); \
  { _Pragma("unroll") for (int f=0; f<4; f++) \
    { _Pragma("unroll") for (int nf=0; nf<4; nf++) \
      acc[f][nf] = __builtin_amdgcn_mfma_f32_16x16x32_bf16(AA[f], BB[nf], acc[f][nf], 0,0,0); } } \
  __builtin_amdgcn_s_setprio(0);

#define BAR_LGKM \
  __builtin_amdgcn_s_barrier(); \
  __builtin_amdgcn_sched_barrier(0); \
  asm volatile("s_waitcnt lgkmcnt(0)" ::: "memory"); \
  __builtin_amdgcn_sched_barrier(0);

#define WAITV(N) asm volatile("s_waitcnt vmcnt(" #N ")" ::: "memory");
#define ORDER_FENCE __builtin_amdgcn_sched_barrier(0); asm volatile("" ::: "memory");

template<bool OUT_BF16>
__global__ __launch_bounds__(512) void k_gemm128x256(
    const u16* __restrict__ A, const u16* __restrict__ Bt,
    const float* __restrict__ bias, void* __restrict__ Cout,
    int M, int N, int K, int nbnx)   // nbnx = (N/256)/8 = bn-panels per XCD
{
  __shared__ __attribute__((aligned(16))) u16 sA[3][2][4096];
  __shared__ __attribute__((aligned(16))) u16 sB[3][2][8192];
  int orig = blockIdx.x;
  int xcd = orig & 7;
  int idx = orig >> 3;
  int bnx = idx % nbnx;
  int bm  = idx / nbnx;
  int bn  = xcd*nbnx + bnx;            // B-panel set per XCD: nbnx panels (L2-resident)
  const int tid = threadIdx.x;
  const int wid = tid>>6, l = tid&63;
  const int lr = l&15, lg = l>>4;
  const int wm = wid>>2, wn = wid&3;   // 2 x 4 wave grid, wave tile 64x64
  const int rba = wm*64, rbb = wn*64;

  // staging source offsets (inverse of the slab swizzle); off0 also serves A
  uint32_t off0, off1;
  { int cc=tid;     int rp=cc>>3, cb=(cc&7)^(rp&7); off0 = (uint32_t)((rp*2+(cb>>2))*K + (cb&3)*8); }
  { int cc=512+tid; int rp=cc>>3, cb=(cc&7)^(rp&7); off1 = (uint32_t)((rp*2+(cb>>2))*K + (cb&3)*8); }
  const u16* Ab = A + (size_t)bm*128*K;
  const u16* Bb = Bt + (size_t)bn*256*K;

  f32x4 acc[4][4] = {};
  bf16x8 a0[4], a1[4], b0[4], b1[4];
  const int NT = K>>6;   // K-tiles of 64 (K multiple of 64, NT>=3)

  // prologue: pairs (0,kh0),(0,kh1),(1,kh0); order pinned between pairs
  STG_B(&sB[0][0][0], Bb);      STG_A(&sA[0][0][0], Ab);      ORDER_FENCE;
  STG_B(&sB[0][1][0], Bb+32);   STG_A(&sA[0][1][0], Ab+32);   ORDER_FENCE;
  STG_B(&sB[1][0][0], Bb+64);   STG_A(&sA[1][0][0], Ab+64);
  WAITV(6);                    // certify (0,kh0)
  __builtin_amdgcn_s_barrier();
  __builtin_amdgcn_sched_barrier(0);

  int s0=0, s1=1, s2=2;
  for (int t=0; t<=NT-3; ++t){
    const u16* A1 = Ab + (t+1)*64;  const u16* B1 = Bb + (t+1)*64;
    const u16* A2 = Ab + (t+2)*64;  const u16* B2 = Bb + (t+2)*64;
    // ---- phase kh0: read pair (t,kh0); stage pair (t+1,kh1)
    RD4(&sB[s0][0][0], rbb, b0); RD4(&sA[s0][0][0], rba, a0);
    STG_B(&sB[s1][1][0], B1+32); STG_A(&sA[s1][1][0], A1+32);
    WAITV(6);                  // certify (t,kh1)
    BAR_LGKM; MM16(a0, b0);
    // ---- phase kh1: read pair (t,kh1); stage pair (t+2,kh0)
    RD4(&sB[s0][1][0], rbb, b1); RD4(&sA[s0][1][0], rba, a1);
    STG_B(&sB[s2][0][0], B2);    STG_A(&sA[s2][0][0], A2);
    WAITV(6);                  // certify (t+1,kh0)
    BAR_LGKM; MM16(a1, b1);
    int tmp=s0; s0=s1; s1=s2; s2=tmp;
  }
  { // ---- t = NT-2: stage only (NT-1,kh1); drain 6 -> 3
    const u16* A1 = Ab + (NT-1)*64;  const u16* B1 = Bb + (NT-1)*64;
    RD4(&sB[s0][0][0], rbb, b0); RD4(&sA[s0][0][0], rba, a0);
    STG_B(&sB[s1][1][0], B1+32); STG_A(&sA[s1][1][0], A1+32);
    WAITV(6);
    BAR_LGKM; MM16(a0, b0);
    RD4(&sB[s0][1][0], rbb, b1); RD4(&sA[s0][1][0], rba, a1);
    WAITV(3);
    BAR_LGKM; MM16(a1, b1);
  }
  { // ---- t = NT-1: no staging; drain 3 -> 0
    RD4(&sB[s1][0][0], rbb, b0); RD4(&sA[s1][0][0], rba, a0);
    WAITV(0);
    BAR_LGKM; MM16(a0, b0);
    RD4(&sB[s1][1][0], rbb, b1); RD4(&sA[s1][1][0], rba, a1);
    BAR_LGKM; MM16(a1, b1);
  }

  // epilogue
  #pragma unroll
  for (int nf=0; nf<4; nf++){
    int col = bn*256 + wn*64 + nf*16 + lr;
    float bv = bias[col];
    #pragma unroll
    for (int m=0; m<4; m++){
      #pragma unroll
      for (int j=0; j<4; j++){
        int row = bm*128 + wm*64 + m*16 + lg*4 + j;  // C/D map: col=lane&15, row=(lane>>4)*4+reg
        float v = acc[m][nf][j] + bv;
        if (OUT_BF16) ((u16*)Cout)[(size_t)row*N + col] = f2bf(v);
        else          ((float*)Cout)[(size_t)row*N + col] = v;
      }
    }
  }
}

// ---------------- GEMM2: 128x128 2-phase (proven) + XCD-local bn ----------------
template<bool OUT_BF16>
__global__ __launch_bounds__(256) void k_gemm_bt(
    const u16* __restrict__ A, const u16* __restrict__ Bt,
    const float* __restrict__ bias, void* __restrict__ Cout,
    int M, int N, int K, int nbnx)   // nbnx = (N/128)/8
{
  __shared__ __attribute__((aligned(16))) u16 sA2[128*64];
  __shared__ __attribute__((aligned(16))) u16 sB2[128*64];
  int orig = blockIdx.x;
  int xcd = orig & 7;
  int idx = orig >> 3;
  int bn  = xcd*nbnx + idx % nbnx;
  int bm  = idx / nbnx;
  const int tid = threadIdx.x;
  const int w = tid>>6, l = tid&63;
  const int lr = l&15, lg = l>>4;
  const int wr = (w>>1)*64, wc = (w&1)*64;
  const size_t rowA = (size_t)bm*128;
  const size_t rowB = (size_t)bn*128;
  f32x4 acc[4][4] = {};
  for (int k0=0; k0<K; k0+=64){
    #pragma unroll
    for (int it=0; it<4; ++it){
      int c = it*256 + tid;
      int r = c>>3, k8 = (c&7) ^ (r&7);
      gload_lds16(A + (rowA+r)*K + k0 + k8*8, &sA2[c*8]);
    }
    #pragma unroll
    for (int it=0; it<4; ++it){
      int c = it*256 + tid;
      int r = c>>3, k8 = (c&7) ^ (r&7);
      gload_lds16(Bt + (rowB+r)*K + k0 + k8*8, &sB2[c*8]);
    }
    __syncthreads();
    #pragma unroll
    for (int ks=0; ks<2; ++ks){
      bf16x8 af[4], bfr[4];
      #pragma unroll
      for (int m=0;m<4;m++){
        int row = wr + m*16 + lr, k = ks*32 + lg*8;
        int byt = ((row<<7) + (k<<1)) ^ ((row&7)<<4);
        af[m] = *(const bf16x8*)((const char*)sA2 + byt);
      }
      #pragma unroll
      for (int n=0;n<4;n++){
        int row = wc + n*16 + lr, k = ks*32 + lg*8;
        int byt = ((row<<7) + (k<<1)) ^ ((row&7)<<4);
        bfr[n] = *(const bf16x8*)((const char*)sB2 + byt);
      }
      #pragma unroll
      for (int m=0;m<4;m++)
        #pragma unroll
        for (int n=0;n<4;n++)
          acc[m][n] = __builtin_amdgcn_mfma_f32_16x16x32_bf16(af[m], bfr[n], acc[m][n], 0,0,0);
    }
    __syncthreads();
  }
  #pragma unroll
  for (int n=0;n<4;n++){
    int col = bn*128 + wc + n*16 + lr;
    float bv = bias[col];
    #pragma unroll
    for (int m=0;m<4;m++){
      #pragma unroll
      for (int j=0;j<4;j++){
        int row = bm*128 + wr + m*16 + lg*4 + j;
        float v = acc[m][n][j] + bv;
        if (OUT_BF16) ((u16*)Cout)[(size_t)row*N + col] = f2bf(v);
        else          ((float*)Cout)[(size_t)row*N + col] = v;
      }
    }
  }
}

// ---------------- pointwise: RMSNorm + RoPE(q,k), value mix, V-transpose, v1 passthrough ----------------
DEVI void unpack16(const u16* p, float* f){
  bf16x8 a = *(const bf16x8*)p, b = *(const bf16x8*)(p+8);
  #pragma unroll
  for (int i=0;i<8;i++){ f[i]=bf2f((u16)a[i]); f[8+i]=bf2f((u16)b[i]); }
}

__global__ __launch_bounds__(256) void k_qkv_post(
    const u16*  __restrict__ qkv,   // [4096][6144] bf16
    const float* __restrict__ v1,   // [B][T][16][128] f32
    const float* __restrict__ lambp,
    u16* __restrict__ qn,           // [4096][2048]
    u16* __restrict__ kn,           // [4096][2048]
    u16* __restrict__ vT,           // [B][16][128][1024]
    float* __restrict__ v1out)      // passthrough copy of v1 (output 1)
{
  __shared__ float cosv[64], sinv[64];
  __shared__ __attribute__((aligned(16))) u16 sv[64][136];  // value tile [t][d], padded
  int bid = blockIdx.x;
  int tb = bid & 15, h = (bid>>4)&15, b = bid>>8;
  int tid = threadIdx.x;
  if (tid < 64){
    // freqs[h][j] = h * 10000^(-j/64);  log2(10000)/64 = 0.20762050593045951
    float ang = (float)h * exp2f(-(float)tid * 0.2076205059304595f);
    cosv[tid] = cosf(ang);
    sinv[tid] = sinf(ang);
  }
  float lamb = lambp[0];
  int row = tid>>2, p = tid&3;
  int t = tb*64 + row;
  size_t base = ((size_t)(b*1024 + t))*6144 + (size_t)h*128;
  __syncthreads();

  // q and k: RMSNorm then RoPE (RoPE is linear -> scale commutes)
  #pragma unroll
  for (int qc=0; qc<2; ++qc){
    const u16* src = qkv + base + qc*2048;
    u16* dst = (qc==0 ? qn : kn) + ((size_t)(b*1024+t))*2048 + h*128;
    int j0 = p*16;
    float x1[16], x2[16];
    unpack16(src + j0, x1);
    unpack16(src + 64 + j0, x2);
    float ss = 0.f;
    #pragma unroll
    for (int i=0;i<16;i++) ss += x1[i]*x1[i] + x2[i]*x2[i];
    ss += __shfl_xor(ss, 1);
    ss += __shfl_xor(ss, 2);
    float rn = rsqrtf(ss*(1.0f/128.0f) + 1e-6f);
    bf16x8 o1a,o1b,o2a,o2b;
    #pragma unroll
    for (int i=0;i<16;i++){
      float c = cosv[j0+i], s = sinv[j0+i];
      u16 a = f2bf(( x1[i]*c + x2[i]*s)*rn);
      u16 bq= f2bf((-x1[i]*s + x2[i]*c)*rn);
      if (i<8){ o1a[i]=(short)a; o2a[i]=(short)bq; } else { o1b[i-8]=(short)a; o2b[i-8]=(short)bq; }
    }
    *(bf16x8*)(dst + j0)      = o1a;
    *(bf16x8*)(dst + j0 + 8)  = o1b;
    *(bf16x8*)(dst + 64 + j0)     = o2a;
    *(bf16x8*)(dst + 64 + j0 + 8) = o2b;
  }

  // value = (1-lamb)*v + lamb*v1  -> LDS tile (for transpose); also v1 passthrough
  {
    const u16* srcv = qkv + base + 4096;
    size_t v1off = (((size_t)(b*1024+t))*16 + h)*128;
    const float* src1 = v1 + v1off;
    float* dst1 = v1out + v1off;
    int d0 = p*32;
    #pragma unroll
    for (int c8=0;c8<4;c8++){
      bf16x8 vv = *(const bf16x8*)(srcv + d0 + c8*8);
      f32x4 a0 = *(const f32x4*)(src1 + d0 + c8*8);
      f32x4 a1 = *(const f32x4*)(src1 + d0 + c8*8 + 4);
      *(f32x4*)(dst1 + d0 + c8*8) = a0;
      *(f32x4*)(dst1 + d0 + c8*8 + 4) = a1;
      bf16x8 o;
      #pragma unroll
      for (int i=0;i<8;i++){
        float x1v = (i<4)? a0[i] : a1[i-4];
        o[i] = (short)f2bf((1.0f-lamb)*bf2f((u16)vv[i]) + lamb*x1v);
      }
      *(bf16x8*)(&sv[row][d0 + c8*8]) = o;
    }
  }
  __syncthreads();
  // write vT[b][h][d][t]
  {
    int d = tid>>1, tc = (tid&1)*32;
    u16 tmp[32];
    #pragma unroll
    for (int i=0;i<32;i++) tmp[i] = sv[tc+i][d];
    u16* dst = vT + (((size_t)(b*16+h))*128 + d)*1024 + tb*64 + tc;
    #pragma unroll
    for (int c8=0;c8<4;c8++){
      bf16x8 o;
      #pragma unroll
      for (int i=0;i<8;i++) o[i]=(short)tmp[c8*8+i];
      *(bf16x8*)(dst + c8*8) = o;
    }
  }
}

// ---------------- flash attention (causal), QBLK=128, 8 waves, pipelined ----------------
// 512 blocks: bids 0-255 -> qip {7,6,5,4}; 256-511 -> qip {0,1,2,3} (complement pairing:
// round-robin CU fill puts (16+2),(14+4),(12+6),(10+8) tile-pairs on each CU).
// Same-bh blocks are 64 apart -> same XCD -> K/V (512KB x 8 bh) L2-resident.
// LDS 80KB = 2 blocks/CU; __launch_bounds__(512,4) caps VGPR at 128 for 16 waves/CU.
__global__ __launch_bounds__(512, 4) void k_attn(
    const u16* __restrict__ Q,   // [4096][2048] (b,t,h,d)
    const u16* __restrict__ Kn,  // same
    const u16* __restrict__ Vt,  // [B][16][128][1024]
    u16* __restrict__ O)         // [4096][2048]
{
  __shared__ __attribute__((aligned(16))) u16 sK[2][64*128];
  __shared__ __attribute__((aligned(16))) u16 sV[2][128*64];
  __shared__ __attribute__((aligned(16))) u16 sP[8][16*64];
  int bid = blockIdx.x;
  int qip = (bid < 256) ? (7 - (bid>>6)) : ((bid>>6) - 4);
  int bh  = bid & 63;
  int h = bh & 15, b = bh >> 4;
  int tid = threadIdx.x, w = tid>>6, l = tid&63, lr = l&15, lg = l>>4;
  int qrow = qip*128 + w*16;
  bf16x8 aq[4];
  {
    const u16* qp = Q + ((size_t)(b*1024 + qrow + lr))*2048 + h*128 + lg*8;
    #pragma unroll
    for (int ks=0; ks<4; ++ks) aq[ks] = *(const bf16x8*)(qp + ks*32);
  }
  f32x4 accO[8] = {};
  float mrun[4], srun[4];
  #pragma unroll
  for (int j=0;j<4;j++){ mrun[j] = -INFINITY; srun[j]=0.f; }
  const float scale = 0.08838834764831845f;   // 1/sqrt(128)
  const size_t kbase = (size_t)(b*1024)*2048 + (size_t)h*128;
  const u16* vbase = Vt + ((size_t)(b*16+h))*128*1024;

  auto STAGE = [&](int kt, int buf){
    #pragma unroll
    for (int it=0; it<2; ++it){           // K tile: [64 key][128 d], swizzled source
      int c = it*512+tid;
      int key = c>>4, d16 = (c&15)^(key&7);
      gload_lds16(Kn + kbase + (size_t)(kt*64+key)*2048 + d16*8, &sK[buf][c*8]);
    }
    #pragma unroll
    for (int it=0; it<2; ++it){           // V tile: [128 d][64 key]
      int c = it*512+tid;
      int d = c>>3, k8 = (c&7)^(d&7);
      gload_lds16(vbase + (size_t)d*1024 + kt*64 + k8*8, &sV[buf][c*8]);
    }
  };

  const int NTT = 2*qip + 2;   // 64-key tiles for this q-block
  STAGE(0, 0);
  int cur = 0;
  for (int kt=0; kt<NTT; ++kt){
    if (kt < NTT-1){
      STAGE(kt+1, cur^1);                            // prefetch next tile
      asm volatile("s_waitcnt vmcnt(4)" ::: "memory"); // wait current tile only
    } else {
      asm volatile("s_waitcnt vmcnt(0)" ::: "memory");
    }
    __builtin_amdgcn_s_barrier();
    __builtin_amdgcn_sched_barrier(0);
    const char* kb = (const char*)sK[cur];
    const char* vb = (const char*)sV[cur];

    f32x4 accS[4] = {};
    __builtin_amdgcn_s_setprio(1);
    #pragma unroll
    for (int ks=0; ks<4; ++ks){
      #pragma unroll
      for (int n=0;n<4;n++){
        int key = n*16+lr, k = ks*32+lg*8;
        int byt = ((key<<8) + (k<<1)) ^ ((key&7)<<4);
        bf16x8 bk = *(const bf16x8*)(kb + byt);
        accS[n] = __builtin_amdgcn_mfma_f32_16x16x32_bf16(aq[ks], bk, accS[n], 0,0,0);
      }
    }
    __builtin_amdgcn_s_setprio(0);
    bool diag = (kt >= 2*qip);
    float pj[4][4];
    #pragma unroll
    for (int j=0;j<4;j++){
      int qg = qrow + lg*4 + j;
      float mx = -INFINITY;
      #pragma unroll
      for (int n=0;n<4;n++){
        float s = accS[n][j]*scale;
        if (diag && (kt*64 + n*16 + lr) > qg) s = -1e30f;
        pj[n][j] = s;
        mx = fmaxf(mx, s);
      }
      #pragma unroll
      for (int off=1; off<16; off<<=1) mx = fmaxf(mx, __shfl_xor(mx, off));
      float mnew = fmaxf(mrun[j], mx);
      float fac = __expf(mrun[j] - mnew);
      float ps = 0.f;
      #pragma unroll
      for (int n=0;n<4;n++){ float e = __expf(pj[n][j]-mnew); pj[n][j]=e; ps += e; }
      #pragma unroll
      for (int off=1; off<16; off<<=1) ps += __shfl_xor(ps, off);
      srun[j] = srun[j]*fac + ps;
      mrun[j] = mnew;
      #pragma unroll
      for (int n=0;n<8;n++) accO[n][j] *= fac;
    }
    // P -> wave-private swizzled LDS (A-operand layout for PV)
    #pragma unroll
    for (int n=0;n<4;n++)
      #pragma unroll
      for (int j=0;j<4;j++){
        int q = lg*4+j, key = n*16+lr;
        int byt = ((q<<7) + (key<<1)) ^ ((q&7)<<4);
        *(u16*)((char*)sP[w] + byt) = f2bf(pj[n][j]);
      }
    bf16x8 pA[2];
    #pragma unroll
    for (int ks=0; ks<2; ++ks){
      int k = ks*32 + lg*8;
      int byt = ((lr<<7) + (k<<1)) ^ ((lr&7)<<4);
      pA[ks] = *(const bf16x8*)((const char*)sP[w] + byt);
    }
    __builtin_amdgcn_s_setprio(1);
    #pragma unroll
    for (int ks=0; ks<2; ++ks)
      #pragma unroll
      for (int n=0;n<8;n++){
        int d = n*16+lr, k = ks*32+lg*8;
        int byt = ((d<<7) + (k<<1)) ^ ((d&7)<<4);
        bf16x8 bv = *(const bf16x8*)(vb + byt);
        accO[n] = __builtin_amdgcn_mfma_f32_16x16x32_bf16(pA[ks], bv, accO[n], 0,0,0);
      }
    __builtin_amdgcn_s_setprio(0);
    __builtin_amdgcn_s_barrier();   // protect buf[cur^1]-compute vs next STAGE overwrite
    cur ^= 1;
  }
  #pragma unroll
  for (int j=0;j<4;j++){
    float inv = 1.0f / srun[j];
    int row = qrow + lg*4 + j;
    u16* op = O + ((size_t)(b*1024+row))*2048 + h*128;
    #pragma unroll
    for (int n=0;n<8;n++)
      op[n*16+lr] = f2bf(accO[n][j]*inv);
  }
}

// ---------------- launch ----------------
extern "C" void kernel_launch(void* const* d_in, const int* in_sizes, int n_in,
                              void* d_out, int out_size, void* d_ws, size_t ws_size,
                              hipStream_t stream)
{
  const float* x     = (const float*)d_in[0];
  const float* v1    = (const float*)d_in[1];
  const float* Wqkv  = (const float*)d_in[2];
  const float* bqkv  = (const float*)d_in[3];
  const float* Wproj = (const float*)d_in[4];
  const float* bproj = (const float*)d_in[5];
  const float* lamb  = (const float*)d_in[6];

  char* ws = (char*)d_ws;
  u16* qkv_b  = (u16*)(ws);                // 50,331,648 B  [4096][6144]
  u16* WqkvT  = (u16*)(ws +  50331648);    // 25,165,824 B  [6144][2048]
  u16* WprojT = (u16*)(ws +  75497472);    //  8,388,608 B  [2048][2048]
  u16* xb     = (u16*)(ws +  83886080);    // 16,777,216 B  [4096][2048] (reused as vT)
  u16* vT     = xb;                        // alias: xb dead after GEMM1
  u16* qn     = (u16*)(ws + 100663296);    // 16,777,216 B
  u16* kn     = (u16*)(ws + 117440512);    // 16,777,216 B   (total 128 MiB)
  u16* attn_b = qkv_b;                     // alias: qkv dead after pointwise

  float* out = (float*)d_out;

  hipLaunchKernelGGL(k_prep, dim3(2048+12288+4096), dim3(256), 0, stream,
                     x, xb, Wqkv, WqkvT, Wproj, WprojT);
  hipLaunchKernelGGL((k_gemm128x256<true>),  dim3(768), dim3(512), 0, stream, xb, WqkvT, bqkv, (void*)qkv_b, 4096, 6144, 2048, 3);
  hipLaunchKernelGGL(k_qkv_post, dim3(1024), dim3(256), 0, stream, qkv_b, v1, lamb, qn, kn, vT, out + 8388608);
  hipLaunchKernelGGL(k_attn, dim3(512), dim3(512), 0, stream, qn, kn, vT, attn_b);
  hipLaunchKernelGGL((k_gemm_bt<false>), dim3(512), dim3(256), 0, stream, attn_b, WprojT, bproj, (void*)out, 4096, 2048, 2048, 2);
}

// Round 14
// 273.029 us; speedup vs baseline: 1.2864x; 1.2864x over previous
//
#include <hip/hip_runtime.h>
#include <stdint.h>
#include <stddef.h>

typedef unsigned short u16;
typedef __attribute__((ext_vector_type(8))) short  bf16x8;   // 8 bf16 = 4 VGPR (MFMA A/B frag)
typedef __attribute__((ext_vector_type(4))) unsigned short u16x4;
typedef __attribute__((ext_vector_type(4))) float  f32x4;

#define DEVI __device__ __forceinline__

DEVI float bf2f(u16 u){ union{uint32_t i; float f;} v; v.i = ((uint32_t)u)<<16; return v.f; }
DEVI u16 f2bf(float f){ union{float f; uint32_t i;} v; v.f=f; uint32_t r = v.i + 0x7fffu + ((v.i>>16)&1u); return (u16)(r>>16); }

DEVI void gload_lds16(const void* g, void* l){
  __builtin_amdgcn_global_load_lds((const __attribute__((address_space(1))) void*)g,
                                   (__attribute__((address_space(3))) void*)l, 16, 0, 0);
}

// ---------------- fused prep: x->bf16 cvt + Wqkv^T + Wproj^T (one launch) ----------------
__global__ __launch_bounds__(256) void k_prep(
    const float* __restrict__ x,     u16* __restrict__ xb,
    const float* __restrict__ Wqkv,  u16* __restrict__ WqkvT,
    const float* __restrict__ Wproj, u16* __restrict__ WprojT)
{
  __shared__ float tile[32][33];
  int bid = blockIdx.x;
  int tid = threadIdx.x;
  if (bid < 2048){                       // cvt x (8,388,608 f32)
    int i = (bid*256 + tid)*4;
    const int st = 2048*256*4;
    for (; i < 8388608; i += st){
      f32x4 v = *(const f32x4*)(x + i);
      u16x4 o;
      #pragma unroll
      for (int j=0;j<4;j++) o[j] = f2bf(v[j]);
      *(u16x4*)(xb + i) = o;
    }
    return;
  }
  const float* in; u16* out; int K, N, nb, kb;
  if (bid < 2048 + 12288){               // Wqkv [2048][6144] -> [6144][2048]
    int b2 = bid - 2048; in = Wqkv; out = WqkvT; K = 2048; N = 6144;
    nb = (b2 % 192)*32; kb = (b2 / 192)*32;
  } else {                               // Wproj [2048][2048] -> [2048][2048]
    int b3 = bid - 2048 - 12288; in = Wproj; out = WprojT; K = 2048; N = 2048;
    nb = (b3 % 64)*32; kb = (b3 / 64)*32;
  }
  int tx = tid & 31, ty = tid >> 5;
  #pragma unroll
  for (int i=0;i<32;i+=8)
    tile[ty+i][tx] = in[(size_t)(kb+ty+i)*N + nb+tx];
  __syncthreads();
  #pragma unroll
  for (int i=0;i<32;i+=8)
    out[(size_t)(nb+ty+i)*K + kb+tx] = f2bf(tile[tx][ty+i]);
}

// ================= 128x256 8-wave GEMM, 2-phase/K-tile, 3-deep slab rotation ==========
// R8-exact (proven 121 us GEMM1, best total 273.1). XCD-local bn-chunk mapping:
// each XCD owns nbnx B-panels (GEMM1: 3 = 3MB, GEMM2: 1 = 1MB <= 4MB L2).
// Slabs: A[3][2][128x32] 48KB, B[3][2][256x32] 96KB = 144 KiB. Row-pair XOR swizzle:
//   byte(row,k16) = (row>>1)*128 + (((((row&1)<<2)|k16) ^ ((row>>1)&7))<<4)
// Stage plan: phase (t,kh0) stages pair (t+1,kh1); phase (t,kh1) stages pair (t+2,kh0).
// vmcnt ledger (3 loads/pair): steady 3 pairs outstanding; WAITV(6) certifies next pair.
#define STG_A(SLAB, GSRC) \
  gload_lds16((GSRC) + off0, (SLAB) + tid*8);
#define STG_B(SLAB, GSRC) \
  gload_lds16((GSRC) + off0, (SLAB) + tid*8); \
  gload_lds16((GSRC) + off1, (SLAB) + 4096 + tid*8);

#define RD4(SLAB, ROWBASE, DST) \
  { _Pragma("unroll") for (int f=0; f<4; f++){ \
      int row_ = (ROWBASE) + f*16 + lr; \
      int rp_ = row_>>1; \
      int slot_ = ((((row_&1)<<2) | lg) ^ (rp_&7)); \
      DST[f] = *(const bf16x8*)((const char*)(SLAB) + rp_*128 + slot_*16); } }

#define MM16(AA, BB) \
  __builtin_amdgcn_s_setprio(1); \
  { _Pragma("unroll") for (int f=0; f<4; f++) \
    { _Pragma("unroll") for (int nf=0; nf<4; nf++) \
      acc[f][nf] = __builtin_amdgcn_mfma_f32_16x16x32_bf16(AA[f], BB[nf], acc[f][nf], 0,0,0); } } \
  __builtin_amdgcn_s_setprio(0);

#define BAR_LGKM \
  __builtin_amdgcn_s_barrier(); \
  __builtin_amdgcn_sched_barrier(0); \
  asm volatile("s_waitcnt lgkmcnt(0)" ::: "memory"); \
  __builtin_amdgcn_sched_barrier(0);

#define WAITV(N) asm volatile("s_waitcnt vmcnt(" #N ")" ::: "memory");
#define ORDER_FENCE __builtin_amdgcn_sched_barrier(0); asm volatile("" ::: "memory");

template<bool OUT_BF16>
__global__ __launch_bounds__(512) void k_gemm128x256(
    const u16* __restrict__ A, const u16* __restrict__ Bt,
    const float* __restrict__ bias, void* __restrict__ Cout,
    int M, int N, int K, int nbnx)   // nbnx = (N/256)/8 = bn-panels per XCD
{
  __shared__ __attribute__((aligned(16))) u16 sA[3][2][4096];
  __shared__ __attribute__((aligned(16))) u16 sB[3][2][8192];
  int orig = blockIdx.x;
  int xcd = orig & 7;
  int idx = orig >> 3;
  int bnx = idx % nbnx;
  int bm  = idx / nbnx;
  int bn  = xcd*nbnx + bnx;            // B-panel set per XCD: nbnx panels (L2-resident)
  const int tid = threadIdx.x;
  const int wid = tid>>6, l = tid&63;
  const int lr = l&15, lg = l>>4;
  const int wm = wid>>2, wn = wid&3;   // 2 x 4 wave grid, wave tile 64x64
  const int rba = wm*64, rbb = wn*64;

  // staging source offsets (inverse of the slab swizzle); off0 also serves A
  uint32_t off0, off1;
  { int cc=tid;     int rp=cc>>3, cb=(cc&7)^(rp&7); off0 = (uint32_t)((rp*2+(cb>>2))*K + (cb&3)*8); }
  { int cc=512+tid; int rp=cc>>3, cb=(cc&7)^(rp&7); off1 = (uint32_t)((rp*2+(cb>>2))*K + (cb&3)*8); }
  const u16* Ab = A + (size_t)bm*128*K;
  const u16* Bb = Bt + (size_t)bn*256*K;

  f32x4 acc[4][4] = {};
  bf16x8 a0[4], a1[4], b0[4], b1[4];
  const int NT = K>>6;   // K-tiles of 64 (K multiple of 64, NT>=3)

  // prologue: pairs (0,kh0),(0,kh1),(1,kh0); order pinned between pairs
  STG_B(&sB[0][0][0], Bb);      STG_A(&sA[0][0][0], Ab);      ORDER_FENCE;
  STG_B(&sB[0][1][0], Bb+32);   STG_A(&sA[0][1][0], Ab+32);   ORDER_FENCE;
  STG_B(&sB[1][0][0], Bb+64);   STG_A(&sA[1][0][0], Ab+64);
  WAITV(6);                    // certify (0,kh0)
  __builtin_amdgcn_s_barrier();
  __builtin_amdgcn_sched_barrier(0);

  int s0=0, s1=1, s2=2;
  for (int t=0; t<=NT-3; ++t){
    const u16* A1 = Ab + (t+1)*64;  const u16* B1 = Bb + (t+1)*64;
    const u16* A2 = Ab + (t+2)*64;  const u16* B2 = Bb + (t+2)*64;
    // ---- phase kh0: read pair (t,kh0); stage pair (t+1,kh1)
    RD4(&sB[s0][0][0], rbb, b0); RD4(&sA[s0][0][0], rba, a0);
    STG_B(&sB[s1][1][0], B1+32); STG_A(&sA[s1][1][0], A1+32);
    WAITV(6);                  // certify (t,kh1)
    BAR_LGKM; MM16(a0, b0);
    // ---- phase kh1: read pair (t,kh1); stage pair (t+2,kh0)
    RD4(&sB[s0][1][0], rbb, b1); RD4(&sA[s0][1][0], rba, a1);
    STG_B(&sB[s2][0][0], B2);    STG_A(&sA[s2][0][0], A2);
    WAITV(6);                  // certify (t+1,kh0)
    BAR_LGKM; MM16(a1, b1);
    int tmp=s0; s0=s1; s1=s2; s2=tmp;
  }
  { // ---- t = NT-2: stage only (NT-1,kh1); drain 6 -> 3
    const u16* A1 = Ab + (NT-1)*64;  const u16* B1 = Bb + (NT-1)*64;
    RD4(&sB[s0][0][0], rbb, b0); RD4(&sA[s0][0][0], rba, a0);
    STG_B(&sB[s1][1][0], B1+32); STG_A(&sA[s1][1][0], A1+32);
    WAITV(6);
    BAR_LGKM; MM16(a0, b0);
    RD4(&sB[s0][1][0], rbb, b1); RD4(&sA[s0][1][0], rba, a1);
    WAITV(3);
    BAR_LGKM; MM16(a1, b1);
  }
  { // ---- t = NT-1: no staging; drain 3 -> 0
    RD4(&sB[s1][0][0], rbb, b0); RD4(&sA[s1][0][0], rba, a0);
    WAITV(0);
    BAR_LGKM; MM16(a0, b0);
    RD4(&sB[s1][1][0], rbb, b1); RD4(&sA[s1][1][0], rba, a1);
    BAR_LGKM; MM16(a1, b1);
  }

  // epilogue
  #pragma unroll
  for (int nf=0; nf<4; nf++){
    int col = bn*256 + wn*64 + nf*16 + lr;
    float bv = bias[col];
    #pragma unroll
    for (int m=0; m<4; m++){
      #pragma unroll
      for (int j=0; j<4; j++){
        int row = bm*128 + wm*64 + m*16 + lg*4 + j;  // C/D map: col=lane&15, row=(lane>>4)*4+reg
        float v = acc[m][nf][j] + bv;
        if (OUT_BF16) ((u16*)Cout)[(size_t)row*N + col] = f2bf(v);
        else          ((float*)Cout)[(size_t)row*N + col] = v;
      }
    }
  }
}

// ---------------- pointwise: RMSNorm + RoPE(q,k), value mix, V-transpose, v1 passthrough ----------------
DEVI void unpack16(const u16* p, float* f){
  bf16x8 a = *(const bf16x8*)p, b = *(const bf16x8*)(p+8);
  #pragma unroll
  for (int i=0;i<8;i++){ f[i]=bf2f((u16)a[i]); f[8+i]=bf2f((u16)b[i]); }
}

__global__ __launch_bounds__(256) void k_qkv_post(
    const u16*  __restrict__ qkv,   // [4096][6144] bf16
    const float* __restrict__ v1,   // [B][T][16][128] f32
    const float* __restrict__ lambp,
    u16* __restrict__ qn,           // [4096][2048]
    u16* __restrict__ kn,           // [4096][2048]
    u16* __restrict__ vT,           // [B][16][128][1024]
    float* __restrict__ v1out)      // passthrough copy of v1 (output 1)
{
  __shared__ float cosv[64], sinv[64];
  __shared__ __attribute__((aligned(16))) u16 sv[64][136];  // value tile [t][d], padded
  int bid = blockIdx.x;
  int tb = bid & 15, h = (bid>>4)&15, b = bid>>8;
  int tid = threadIdx.x;
  if (tid < 64){
    // freqs[h][j] = h * 10000^(-j/64);  log2(10000)/64 = 0.20762050593045951
    float ang = (float)h * exp2f(-(float)tid * 0.2076205059304595f);
    cosv[tid] = cosf(ang);
    sinv[tid] = sinf(ang);
  }
  float lamb = lambp[0];
  int row = tid>>2, p = tid&3;
  int t = tb*64 + row;
  size_t base = ((size_t)(b*1024 + t))*6144 + (size_t)h*128;
  __syncthreads();

  // q and k: RMSNorm then RoPE (RoPE is linear -> scale commutes)
  #pragma unroll
  for (int qc=0; qc<2; ++qc){
    const u16* src = qkv + base + qc*2048;
    u16* dst = (qc==0 ? qn : kn) + ((size_t)(b*1024+t))*2048 + h*128;
    int j0 = p*16;
    float x1[16], x2[16];
    unpack16(src + j0, x1);
    unpack16(src + 64 + j0, x2);
    float ss = 0.f;
    #pragma unroll
    for (int i=0;i<16;i++) ss += x1[i]*x1[i] + x2[i]*x2[i];
    ss += __shfl_xor(ss, 1);
    ss += __shfl_xor(ss, 2);
    float rn = rsqrtf(ss*(1.0f/128.0f) + 1e-6f);
    bf16x8 o1a,o1b,o2a,o2b;
    #pragma unroll
    for (int i=0;i<16;i++){
      float c = cosv[j0+i], s = sinv[j0+i];
      u16 a = f2bf(( x1[i]*c + x2[i]*s)*rn);
      u16 bq= f2bf((-x1[i]*s + x2[i]*c)*rn);
      if (i<8){ o1a[i]=(short)a; o2a[i]=(short)bq; } else { o1b[i-8]=(short)a; o2b[i-8]=(short)bq; }
    }
    *(bf16x8*)(dst + j0)      = o1a;
    *(bf16x8*)(dst + j0 + 8)  = o1b;
    *(bf16x8*)(dst + 64 + j0)     = o2a;
    *(bf16x8*)(dst + 64 + j0 + 8) = o2b;
  }

  // value = (1-lamb)*v + lamb*v1  -> LDS tile (for transpose); also v1 passthrough
  {
    const u16* srcv = qkv + base + 4096;
    size_t v1off = (((size_t)(b*1024+t))*16 + h)*128;
    const float* src1 = v1 + v1off;
    float* dst1 = v1out + v1off;
    int d0 = p*32;
    #pragma unroll
    for (int c8=0;c8<4;c8++){
      bf16x8 vv = *(const bf16x8*)(srcv + d0 + c8*8);
      f32x4 a0 = *(const f32x4*)(src1 + d0 + c8*8);
      f32x4 a1 = *(const f32x4*)(src1 + d0 + c8*8 + 4);
      *(f32x4*)(dst1 + d0 + c8*8) = a0;
      *(f32x4*)(dst1 + d0 + c8*8 + 4) = a1;
      bf16x8 o;
      #pragma unroll
      for (int i=0;i<8;i++){
        float x1v = (i<4)? a0[i] : a1[i-4];
        o[i] = (short)f2bf((1.0f-lamb)*bf2f((u16)vv[i]) + lamb*x1v);
      }
      *(bf16x8*)(&sv[row][d0 + c8*8]) = o;
    }
  }
  __syncthreads();
  // write vT[b][h][d][t]
  {
    int d = tid>>1, tc = (tid&1)*32;
    u16 tmp[32];
    #pragma unroll
    for (int i=0;i<32;i++) tmp[i] = sv[tc+i][d];
    u16* dst = vT + (((size_t)(b*16+h))*128 + d)*1024 + tb*64 + tc;
    #pragma unroll
    for (int c8=0;c8<4;c8++){
      bf16x8 o;
      #pragma unroll
      for (int i=0;i<8;i++) o[i]=(short)tmp[c8*8+i];
      *(bf16x8*)(dst + c8*8) = o;
    }
  }
}

// ---------------- flash attention (causal), bf16 MFMA, pipelined (QBLK=64, proven) ----------------
__global__ __launch_bounds__(256) void k_attn(
    const u16* __restrict__ Q,   // [4096][2048] (b,t,h,d)
    const u16* __restrict__ Kn,  // same
    const u16* __restrict__ Vt,  // [B][16][128][1024]
    u16* __restrict__ O)         // [4096][2048]
{
  __shared__ __attribute__((aligned(16))) u16 sK[2][64*128];
  __shared__ __attribute__((aligned(16))) u16 sV[2][128*64];
  __shared__ __attribute__((aligned(16))) u16 sP[4][16*64];
  int bid = blockIdx.x;
  int qi = 15 - (bid>>6);          // heavy q-tiles dispatch first (tail kill)
  int bh = bid & 63;
  int h = bh & 15, b = bh >> 4;
  int tid = threadIdx.x, w = tid>>6, l = tid&63, lr = l&15, lg = l>>4;
  int qrow = qi*64 + w*16;
  bf16x8 aq[4];
  {
    const u16* qp = Q + ((size_t)(b*1024 + qrow + lr))*2048 + h*128 + lg*8;
    #pragma unroll
    for (int ks=0; ks<4; ++ks) aq[ks] = *(const bf16x8*)(qp + ks*32);
  }
  f32x4 accO[8] = {};
  float mrun[4], srun[4];
  #pragma unroll
  for (int j=0;j<4;j++){ mrun[j] = -INFINITY; srun[j]=0.f; }
  const float scale = 0.08838834764831845f;   // 1/sqrt(128)
  const size_t kbase = (size_t)(b*1024)*2048 + (size_t)h*128;
  const u16* vbase = Vt + ((size_t)(b*16+h))*128*1024;

  auto STAGE = [&](int kt, int buf){
    #pragma unroll
    for (int it=0; it<4; ++it){           // K tile: [64 key][128 d], swizzled source
      int c = it*256+tid;
      int key = c>>4, d16 = (c&15)^(key&7);
      gload_lds16(Kn + kbase + (size_t)(kt*64+key)*2048 + d16*8, &sK[buf][c*8]);
    }
    #pragma unroll
    for (int it=0; it<4; ++it){           // V tile: [128 d][64 key]
      int c = it*256+tid;
      int d = c>>3, k8 = (c&7)^(d&7);
      gload_lds16(vbase + (size_t)d*1024 + kt*64 + k8*8, &sV[buf][c*8]);
    }
  };

  STAGE(0, 0);
  int cur = 0;
  for (int kt=0; kt<=qi; ++kt){
    if (kt < qi){
      STAGE(kt+1, cur^1);                            // prefetch next tile
      asm volatile("s_waitcnt vmcnt(8)" ::: "memory"); // wait current tile only
    } else {
      asm volatile("s_waitcnt vmcnt(0)" ::: "memory");
    }
    __builtin_amdgcn_s_barrier();
    __builtin_amdgcn_sched_barrier(0);
    const char* kb = (const char*)sK[cur];
    const char* vb = (const char*)sV[cur];

    f32x4 accS[4] = {};
    __builtin_amdgcn_s_setprio(1);
    #pragma unroll
    for (int ks=0; ks<4; ++ks){
      #pragma unroll
      for (int n=0;n<4;n++){
        int key = n*16+lr, k = ks*32+lg*8;
        int byt = ((key<<8) + (k<<1)) ^ ((key&7)<<4);
        bf16x8 bk = *(const bf16x8*)(kb + byt);
        accS[n] = __builtin_amdgcn_mfma_f32_16x16x32_bf16(aq[ks], bk, accS[n], 0,0,0);
      }
    }
    __builtin_amdgcn_s_setprio(0);
    bool diag = (kt == qi);
    float pj[4][4];
    #pragma unroll
    for (int j=0;j<4;j++){
      int qg = qrow + lg*4 + j;
      float mx = -INFINITY;
      #pragma unroll
      for (int n=0;n<4;n++){
        float s = accS[n][j]*scale;
        if (diag && (kt*64 + n*16 + lr) > qg) s = -1e30f;
        pj[n][j] = s;
        mx = fmaxf(mx, s);
      }
      #pragma unroll
      for (int off=1; off<16; off<<=1) mx = fmaxf(mx, __shfl_xor(mx, off));
      float mnew = fmaxf(mrun[j], mx);
      float fac = __expf(mrun[j] - mnew);
      float ps = 0.f;
      #pragma unroll
      for (int n=0;n<4;n++){ float e = __expf(pj[n][j]-mnew); pj[n][j]=e; ps += e; }
      #pragma unroll
      for (int off=1; off<16; off<<=1) ps += __shfl_xor(ps, off);
      srun[j] = srun[j]*fac + ps;
      mrun[j] = mnew;
      #pragma unroll
      for (int n=0;n<8;n++) accO[n][j] *= fac;
    }
    // P -> wave-private swizzled LDS (A-operand layout for PV)
    #pragma unroll
    for (int n=0;n<4;n++)
      #pragma unroll
      for (int j=0;j<4;j++){
        int q = lg*4+j, key = n*16+lr;
        int byt = ((q<<7) + (key<<1)) ^ ((q&7)<<4);
        *(u16*)((char*)sP[w] + byt) = f2bf(pj[n][j]);
      }
    bf16x8 pA[2];
    #pragma unroll
    for (int ks=0; ks<2; ++ks){
      int k = ks*32 + lg*8;
      int byt = ((lr<<7) + (k<<1)) ^ ((lr&7)<<4);
      pA[ks] = *(const bf16x8*)((const char*)sP[w] + byt);
    }
    __builtin_amdgcn_s_setprio(1);
    #pragma unroll
    for (int ks=0; ks<2; ++ks)
      #pragma unroll
      for (int n=0;n<8;n++){
        int d = n*16+lr, k = ks*32+lg*8;
        int byt = ((d<<7) + (k<<1)) ^ ((d&7)<<4);
        bf16x8 bv = *(const bf16x8*)(vb + byt);
        accO[n] = __builtin_amdgcn_mfma_f32_16x16x32_bf16(pA[ks], bv, accO[n], 0,0,0);
      }
    __builtin_amdgcn_s_setprio(0);
    __builtin_amdgcn_s_barrier();   // protect buf[cur^1]-compute vs next STAGE overwrite
    cur ^= 1;
  }
  #pragma unroll
  for (int j=0;j<4;j++){
    float inv = 1.0f / srun[j];
    int row = qrow + lg*4 + j;
    u16* op = O + ((size_t)(b*1024+row))*2048 + h*128;
    #pragma unroll
    for (int n=0;n<8;n++)
      op[n*16+lr] = f2bf(accO[n][j]*inv);
  }
}

// ---------------- launch ----------------
extern "C" void kernel_launch(void* const* d_in, const int* in_sizes, int n_in,
                              void* d_out, int out_size, void* d_ws, size_t ws_size,
                              hipStream_t stream)
{
  const float* x     = (const float*)d_in[0];
  const float* v1    = (const float*)d_in[1];
  const float* Wqkv  = (const float*)d_in[2];
  const float* bqkv  = (const float*)d_in[3];
  const float* Wproj = (const float*)d_in[4];
  const float* bproj = (const float*)d_in[5];
  const float* lamb  = (const float*)d_in[6];

  char* ws = (char*)d_ws;
  u16* qkv_b  = (u16*)(ws);                // 50,331,648 B  [4096][6144]
  u16* WqkvT  = (u16*)(ws +  50331648);    // 25,165,824 B  [6144][2048]
  u16* WprojT = (u16*)(ws +  75497472);    //  8,388,608 B  [2048][2048]
  u16* xb     = (u16*)(ws +  83886080);    // 16,777,216 B  [4096][2048] (reused as vT)
  u16* vT     = xb;                        // alias: xb dead after GEMM1
  u16* qn     = (u16*)(ws + 100663296);    // 16,777,216 B
  u16* kn     = (u16*)(ws + 117440512);    // 16,777,216 B   (total 128 MiB)
  u16* attn_b = qkv_b;                     // alias: qkv dead after pointwise

  float* out = (float*)d_out;

  hipLaunchKernelGGL(k_prep, dim3(2048+12288+4096), dim3(256), 0, stream,
                     x, xb, Wqkv, WqkvT, Wproj, WprojT);
  hipLaunchKernelGGL((k_gemm128x256<true>),  dim3(768), dim3(512), 0, stream, xb, WqkvT, bqkv, (void*)qkv_b, 4096, 6144, 2048, 3);
  hipLaunchKernelGGL(k_qkv_post, dim3(1024), dim3(256), 0, stream, qkv_b, v1, lamb, qn, kn, vT, out + 8388608);
  hipLaunchKernelGGL(k_attn, dim3(1024), dim3(256), 0, stream, qn, kn, vT, attn_b);
  hipLaunchKernelGGL((k_gemm128x256<false>), dim3(256), dim3(512), 0, stream, attn_b, WprojT, bproj, (void*)out, 4096, 2048, 2048, 1);
}